// Round 12
// baseline (536.306 us; speedup 1.0000x reference)
//
#include <hip/hip_runtime.h>

#define L_SEQ 2048
#define BATCH 16
#define DDIM  1024
#define MDIM  (L_SEQ * BATCH)   // 32768
#define NDIM  (3 * DDIM)        // 3072
#define KDIM  DDIM              // 1024
#define CH    (BATCH * DDIM)    // 16384
#define NSEG  32
#define SEGL  64                // L_SEQ / NSEG

typedef __attribute__((ext_vector_type(8))) short short8;
typedef __attribute__((ext_vector_type(4))) float f32x4;

static __device__ __forceinline__ unsigned short f2bf(float f) {
  unsigned int u = __builtin_bit_cast(unsigned int, f);
  unsigned int lsb = (u >> 16) & 1u;
  u += 0x7fffu + lsb;
  return (unsigned short)(u >> 16);
}
static __device__ __forceinline__ float bf2f(unsigned short s) {
  unsigned int u = ((unsigned int)s) << 16;
  return __builtin_bit_cast(float, u);
}

static __device__ __forceinline__ void gll16(const void* g, void* l) {
  __builtin_amdgcn_global_load_lds(
      (const __attribute__((address_space(1))) unsigned int*)g,
      (__attribute__((address_space(3))) unsigned int*)l, 16, 0, 0);
}

// ---- converters ----------------------------------------------------------

__global__ void k_convert_x(const float4* __restrict__ x, ushort4* __restrict__ xb, int n4) {
  int i = blockIdx.x * blockDim.x + threadIdx.x;
  int stride = gridDim.x * blockDim.x;
  for (; i < n4; i += stride) {
    float4 v = x[i];
    ushort4 o;
    o.x = f2bf(v.x); o.y = f2bf(v.y); o.z = f2bf(v.z); o.w = f2bf(v.w);
    xb[i] = o;
  }
}

// Wb[n][k] = bf16( W[k][colmap(n)] ): regions {xt, f, r} -> contiguous col ranges
__global__ void k_convert_w(const float* __restrict__ w, unsigned short* __restrict__ wb) {
  int gid = blockIdx.x * 256 + threadIdx.x;   // 3072*1024 total
  int k = gid & (KDIM - 1);
  int n = gid >> 10;
  int col = (n < DDIM) ? 3 * n : (n < 2 * DDIM) ? 3 * (n - DDIM) + 1 : 3 * (n - 2 * DDIM) + 2;
  wb[gid] = f2bf(w[(size_t)k * NDIM + col]);
}

// ---- GEMM: barrier-free K-loop. 256x64 tile, 4 waves, B LDS-persistent ---
// R11 post-mortem: 9 structures pinned at ~35% MfmaUtil; the shared invariant
// is block-wide barrier coupling of the staging double-buffer. This kernel
// removes it: B (64 cols x K=1024 = 128 KB) is staged ONCE (single barrier),
// then each wave owns a private 64-row A strip in its own 8 KB LDS buffer,
// reg-staged by itself (8 dwordx4 -> 8 ds_write_b128) with depth-2 prefetch
// (slack ~2 steps = 1240 cyc > 900-cyc HBM miss). ZERO barriers in the loop;
// per-wave counted vmcnt(8); WAR on the A buffer is same-wave in-order DS.
// LDS rows are 128 B with sigma = slot ^ (row&7) XOR permutation
// (conflict-free for frag reads and staging writes; derivation in journal).

#define MFMA1(M, N, A, B) \
  acc[M][N] = __builtin_amdgcn_mfma_f32_16x16x32_bf16(A, B, acc[M][N], 0, 0, 0);

#define STEP(T, P, Q) do {                                                     \
  if ((T) <= 13) {  /* issue A[T+2] into set P (8 x dwordx4) */                \
    P##0 = *(const uint4*)(aSrc + ((T) + 2) * 128);                            \
    P##1 = *(const uint4*)(aSrc +  16384 + ((T) + 2) * 128);                   \
    P##2 = *(const uint4*)(aSrc +  32768 + ((T) + 2) * 128);                   \
    P##3 = *(const uint4*)(aSrc +  49152 + ((T) + 2) * 128);                   \
    P##4 = *(const uint4*)(aSrc +  65536 + ((T) + 2) * 128);                   \
    P##5 = *(const uint4*)(aSrc +  81920 + ((T) + 2) * 128);                   \
    P##6 = *(const uint4*)(aSrc +  98304 + ((T) + 2) * 128);                   \
    P##7 = *(const uint4*)(aSrc + 114688 + ((T) + 2) * 128);                   \
  }                                                                            \
  __builtin_amdgcn_sched_barrier(0);                                           \
  /* A[T] frags from own buffer (addrs T-invariant) */                         \
  a0 = *(const short8*)(LDSc + aRd0);                                          \
  a1 = *(const short8*)(LDSc + aRd0 + 2048);                                   \
  a2 = *(const short8*)(LDSc + aRd0 + 4096);                                   \
  a3 = *(const short8*)(LDSc + aRd0 + 6144);                                   \
  a4 = *(const short8*)(LDSc + aRd1);                                          \
  a5 = *(const short8*)(LDSc + aRd1 + 2048);                                   \
  a6 = *(const short8*)(LDSc + aRd1 + 4096);                                   \
  a7 = *(const short8*)(LDSc + aRd1 + 6144);                                   \
  /* B[T] frags from persistent region */                                      \
  b0 = *(const short8*)(LDSc + bRd0 + (T) * 8192);                             \
  b1 = *(const short8*)(LDSc + bRd0 + (T) * 8192 + 2048);                      \
  b2 = *(const short8*)(LDSc + bRd0 + (T) * 8192 + 4096);                      \
  b3 = *(const short8*)(LDSc + bRd0 + (T) * 8192 + 6144);                      \
  b4 = *(const short8*)(LDSc + bRd1 + (T) * 8192);                             \
  b5 = *(const short8*)(LDSc + bRd1 + (T) * 8192 + 2048);                      \
  b6 = *(const short8*)(LDSc + bRd1 + (T) * 8192 + 4096);                      \
  b7 = *(const short8*)(LDSc + bRd1 + (T) * 8192 + 6144);                      \
  /* counted wait (A[T+1] regs landed), then write A[T+1] over A[T] —         */\
  /* same-wave in-order DS: our reads above precede these writes.             */\
  if ((T) <= 13)      { asm volatile("s_waitcnt vmcnt(8)" ::: "memory"); }     \
  else if ((T) == 14) { asm volatile("s_waitcnt vmcnt(0)" ::: "memory"); }     \
  if ((T) <= 14) {                                                             \
    *(short8*)(aW)        = *(short8*)&Q##0;                                   \
    *(short8*)(aW + 1024) = *(short8*)&Q##1;                                   \
    *(short8*)(aW + 2048) = *(short8*)&Q##2;                                   \
    *(short8*)(aW + 3072) = *(short8*)&Q##3;                                   \
    *(short8*)(aW + 4096) = *(short8*)&Q##4;                                   \
    *(short8*)(aW + 5120) = *(short8*)&Q##5;                                   \
    *(short8*)(aW + 6144) = *(short8*)&Q##6;                                   \
    *(short8*)(aW + 7168) = *(short8*)&Q##7;                                   \
  }                                                                            \
  /* 32 MFMA: kk0 then kk1 */                                                  \
  MFMA1(0, 0, a0, b0) MFMA1(0, 1, a0, b1) MFMA1(0, 2, a0, b2) MFMA1(0, 3, a0, b3) \
  MFMA1(1, 0, a1, b0) MFMA1(1, 1, a1, b1) MFMA1(1, 2, a1, b2) MFMA1(1, 3, a1, b3) \
  MFMA1(2, 0, a2, b0) MFMA1(2, 1, a2, b1) MFMA1(2, 2, a2, b2) MFMA1(2, 3, a2, b3) \
  MFMA1(3, 0, a3, b0) MFMA1(3, 1, a3, b1) MFMA1(3, 2, a3, b2) MFMA1(3, 3, a3, b3) \
  MFMA1(0, 0, a4, b4) MFMA1(0, 1, a4, b5) MFMA1(0, 2, a4, b6) MFMA1(0, 3, a4, b7) \
  MFMA1(1, 0, a5, b4) MFMA1(1, 1, a5, b5) MFMA1(1, 2, a5, b6) MFMA1(1, 3, a5, b7) \
  MFMA1(2, 0, a6, b4) MFMA1(2, 1, a6, b5) MFMA1(2, 2, a6, b6) MFMA1(2, 3, a6, b7) \
  MFMA1(3, 0, a7, b4) MFMA1(3, 1, a7, b5) MFMA1(3, 2, a7, b6) MFMA1(3, 3, a7, b7) \
} while (0)

__global__ __launch_bounds__(256, 1) void k_gemm_nb(
    const unsigned short* __restrict__ xb,   // [M][K] bf16
    const unsigned short* __restrict__ wb,   // [N][K] bf16
    const float* __restrict__ bias,          // [2d]
    unsigned short* __restrict__ xtb,        // [M][d] bf16
    unsigned short* __restrict__ fbuf,       // [M][d] bf16
    unsigned short* __restrict__ rbuf) {     // [M][d] bf16
  __shared__ char LDS[163840];   // [0,32K): A, 4 waves x 8KB  |  [32K,160K): B, 16 x 8KB
  char* LDSc = LDS;

  const int tid  = threadIdx.x;
  const int lane = tid & 63;
  const int wv   = tid >> 6;     // 0..3, owns rows [wv*64, wv*64+64)

  // XCD-aware bijective swizzle: 6144 = 8 * 768; per XCD: 16 mt x 48 nt ->
  // A panel (512 KB) L2-resident across its 48 consumers.
  int bid = blockIdx.x;
  int wg = (bid & 7) * 768 + (bid >> 3);
  int mt = wg / 48;              // 0..127
  int nt = wg - mt * 48;         // 0..47
  const int rowBase = mt * 256;
  const int colBase = nt * 64;

  const int l15 = lane & 15;
  const int sl  = lane >> 4;     // 0..3
  const int l7  = lane & 7;
  const int lr3 = lane >> 3;     // 0..7

  // frag read bases: row = *16 + l15 (so row&7 = l15&7), slot s = kk*4 + sl,
  // phys slot = s ^ (row&7);  A in own 8KB, B at 32768 + T*8192.
  const int fr0 = ((sl)     ^ (l15 & 7)) << 4;
  const int fr1 = ((4 + sl) ^ (l15 & 7)) << 4;
  const int aRd0 = wv * 8192 + l15 * 128 + fr0;
  const int aRd1 = wv * 8192 + l15 * 128 + fr1;
  const int bRd0 = 32768 + l15 * 128 + fr0;
  const int bRd1 = 32768 + l15 * 128 + fr1;

  // A reg-staging: lane covers (row = i*8 + lr3, slot = l7), i = 0..7.
  const char* aSrc = (const char*)xb + (size_t)(rowBase + wv * 64 + lr3) * 2048 + l7 * 16;
  // ds_write: row&7 = lr3 -> sigma lane-invariant; addr(i) = aW + i*1024.
  char* aW = LDSc + wv * 8192 + lr3 * 128 + ((l7 ^ lr3) << 4);

  f32x4 acc[4][4];
#pragma unroll
  for (int ii = 0; ii < 4; ++ii)
#pragma unroll
    for (int jj = 0; jj < 4; ++jj)
      acc[ii][jj] = (f32x4){0.f, 0.f, 0.f, 0.f};

  // ---- prologue: stage ALL of B (128 KB, 32 gll16), inverse-perm source ---
#pragma unroll
  for (int j = 0; j < 32; ++j) {
    int u16 = j * 256 + tid;
    int byteo = u16 << 4;
    int kb  = byteo >> 13;
    int loc = byteo & 8191;
    int r   = loc >> 7;
    int sp  = (loc >> 4) & 7;
    const char* src = (const char*)wb + (size_t)(colBase + r) * 2048 + kb * 128 + ((sp ^ (r & 7)) << 4);
    gll16(src, LDSc + 32768 + (j << 12) + (wv << 10));
  }

  uint4 p0, p1, p2, p3, p4, p5, p6, p7;   // A stage set 0 (even targets)
  uint4 q0, q1, q2, q3, q4, q5, q6, q7;   // A stage set 1 (odd targets)

  // A[0] -> p, A[1] -> q
  p0 = *(const uint4*)(aSrc);
  p1 = *(const uint4*)(aSrc + 16384);
  p2 = *(const uint4*)(aSrc + 32768);
  p3 = *(const uint4*)(aSrc + 49152);
  p4 = *(const uint4*)(aSrc + 65536);
  p5 = *(const uint4*)(aSrc + 81920);
  p6 = *(const uint4*)(aSrc + 98304);
  p7 = *(const uint4*)(aSrc + 114688);
  q0 = *(const uint4*)(aSrc + 128);
  q1 = *(const uint4*)(aSrc + 16384 + 128);
  q2 = *(const uint4*)(aSrc + 32768 + 128);
  q3 = *(const uint4*)(aSrc + 49152 + 128);
  q4 = *(const uint4*)(aSrc + 65536 + 128);
  q5 = *(const uint4*)(aSrc + 81920 + 128);
  q6 = *(const uint4*)(aSrc + 98304 + 128);
  q7 = *(const uint4*)(aSrc + 114688 + 128);
  asm volatile("s_waitcnt vmcnt(16)" ::: "memory");   // all 32 B gll16 retired
  __builtin_amdgcn_s_barrier();                       // the ONLY barrier
  asm volatile("s_waitcnt vmcnt(8)" ::: "memory");    // p (A[0]) landed
  *(short8*)(aW)        = *(short8*)&p0;
  *(short8*)(aW + 1024) = *(short8*)&p1;
  *(short8*)(aW + 2048) = *(short8*)&p2;
  *(short8*)(aW + 3072) = *(short8*)&p3;
  *(short8*)(aW + 4096) = *(short8*)&p4;
  *(short8*)(aW + 5120) = *(short8*)&p5;
  *(short8*)(aW + 6144) = *(short8*)&p6;
  *(short8*)(aW + 7168) = *(short8*)&p7;

  short8 a0, a1, a2, a3, a4, a5, a6, a7;
  short8 b0, b1, b2, b3, b4, b5, b6, b7;

  // barrier-free K-loop: 16 steps of BK=64
  STEP(0, p, q);  STEP(1, q, p);  STEP(2, p, q);  STEP(3, q, p);
  STEP(4, p, q);  STEP(5, q, p);  STEP(6, p, q);  STEP(7, q, p);
  STEP(8, p, q);  STEP(9, q, p);  STEP(10, p, q); STEP(11, q, p);
  STEP(12, p, q); STEP(13, q, p); STEP(14, p, q); STEP(15, q, p);

  // epilogue: region 0 -> x_tilde (bf16), 1 -> forget, 2 -> reset
  const int region = colBase >> 10;
#pragma unroll
  for (int m = 0; m < 4; ++m) {
    int grow = rowBase + wv * 64 + m * 16 + (sl << 2);
#pragma unroll
    for (int n = 0; n < 4; ++n) {
      int gcol = colBase + n * 16 + l15;
      f32x4 v = acc[m][n];
      if (region == 0) {
#pragma unroll
        for (int j = 0; j < 4; ++j)
          xtb[(size_t)(grow + j) * DDIM + gcol] = f2bf(v[j]);
      } else {
        float bv = bias[gcol - DDIM];
        unsigned short* dst = (region == 1) ? fbuf : rbuf;
        int lcol = gcol - (region << 10);
#pragma unroll
        for (int j = 0; j < 4; ++j) {
          float sg = 1.0f / (1.0f + __expf(-(v[j] + bv)));
          dst[(size_t)(grow + j) * DDIM + lcol] = f2bf(sg);
        }
      }
    }
  }
}

// ---- segmented scan (R5 versions — proven) -------------------------------

__global__ __launch_bounds__(256) void k_scan1(
    const unsigned short* __restrict__ fbuf,
    const unsigned short* __restrict__ xtb,
    float4* __restrict__ AB) {
  int chp = blockIdx.x * 256 + threadIdx.x;
  int seg = blockIdx.y;
  size_t base = (size_t)seg * SEGL * CH + chp * 2;
  const unsigned int* fp = (const unsigned int*)(fbuf + base);
  const unsigned int* xp = (const unsigned int*)(xtb + base);
  float a0 = 1.f, a1 = 1.f, b0 = 0.f, b1 = 0.f;
#pragma unroll 8
  for (int s = 0; s < SEGL; ++s) {
    unsigned int fv = fp[(size_t)s * (CH / 2)];
    unsigned int xv = xp[(size_t)s * (CH / 2)];
    float f0 = bf2f((unsigned short)fv), f1 = bf2f((unsigned short)(fv >> 16));
    float x0 = bf2f((unsigned short)xv), x1 = bf2f((unsigned short)(xv >> 16));
    b0 = (b0 - x0) * f0 + x0;  a0 *= f0;
    b1 = (b1 - x1) * f1 + x1;  a1 *= f1;
  }
  AB[(size_t)seg * (CH / 2) + chp] = (float4){a0, b0, a1, b1};
}

__global__ __launch_bounds__(256) void k_scan2(
    const float* __restrict__ c0,
    const float4* __restrict__ AB,
    float* __restrict__ Cin,
    float* __restrict__ clast) {
  int chp = blockIdx.x * 256 + threadIdx.x;
  float2 cc = ((const float2*)c0)[chp];
  float ca = cc.x, cb = cc.y;
#pragma unroll
  for (int s = 0; s < NSEG; ++s) {
    ((float2*)Cin)[(size_t)s * (CH / 2) + chp] = (float2){ca, cb};
    float4 ab = AB[(size_t)s * (CH / 2) + chp];
    ca = ca * ab.x + ab.y;
    cb = cb * ab.z + ab.w;
  }
  ((float2*)clast)[chp] = (float2){ca, cb};
}

__global__ __launch_bounds__(256) void k_scan3(
    const float* __restrict__ x,
    const unsigned short* __restrict__ fbuf,
    const unsigned short* __restrict__ xtb,
    const unsigned short* __restrict__ rbuf,
    const float* __restrict__ Cin,
    float* __restrict__ h) {
  int chp = blockIdx.x * 256 + threadIdx.x;
  int seg = blockIdx.y;
  float2 cc = ((const float2*)Cin)[(size_t)seg * (CH / 2) + chp];
  float ca = cc.x, cb = cc.y;
  size_t base = (size_t)seg * SEGL * CH + chp * 2;
  const unsigned int* fp = (const unsigned int*)(fbuf + base);
  const unsigned int* tp = (const unsigned int*)(xtb + base);
  const unsigned int* rp = (const unsigned int*)(rbuf + base);
  const float2* xp = (const float2*)(x + base);
  float2* hp = (float2*)(h + base);
#pragma unroll 4
  for (int s = 0; s < SEGL; ++s) {
    unsigned int fv = fp[(size_t)s * (CH / 2)];
    unsigned int tv = tp[(size_t)s * (CH / 2)];
    unsigned int rv = rp[(size_t)s * (CH / 2)];
    float2 xv = xp[(size_t)s * (CH / 2)];
    float f0 = bf2f((unsigned short)fv), f1 = bf2f((unsigned short)(fv >> 16));
    float t0 = bf2f((unsigned short)tv), t1 = bf2f((unsigned short)(tv >> 16));
    float r0 = bf2f((unsigned short)rv), r1 = bf2f((unsigned short)(rv >> 16));
    ca = (ca - t0) * f0 + t0;
    cb = (cb - t1) * f1 + t1;
    float e0 = __expf(-2.f * fabsf(ca));
    float e1 = __expf(-2.f * fabsf(cb));
    float g0 = copysignf((1.f - e0) / (1.f + e0), ca);
    float g1 = copysignf((1.f - e1) / (1.f + e1), cb);
    float h0 = (g0 - xv.x) * r0 + xv.x;
    float h1 = (g1 - xv.y) * r1 + xv.y;
    hp[(size_t)s * (CH / 2)] = (float2){h0, h1};
  }
}

// ---- launch --------------------------------------------------------------

extern "C" void kernel_launch(void* const* d_in, const int* in_sizes, int n_in,
                              void* d_out, int out_size, void* d_ws, size_t ws_size,
                              hipStream_t stream) {
  const float* x    = (const float*)d_in[0];
  const float* w    = (const float*)d_in[1];
  const float* bias = (const float*)d_in[2];
  const float* c0   = (const float*)d_in[3];
  float* out = (float*)d_out;
  char* ws = (char*)d_ws;

  unsigned short* wb   = (unsigned short*)(ws);
  float4*         AB   = (float4*)(ws);
  float*          Cin  = (float*)(ws + 4194304);
  unsigned short* xtb  = (unsigned short*)(ws + 6291456);
  unsigned short* fbuf = (unsigned short*)(ws + 73400320);
  unsigned short* rbuf = (unsigned short*)(ws + 140509184);
  unsigned short* xb = (unsigned short*)d_out;   // h-region, dead until scan3

  k_convert_x<<<2048, 256, 0, stream>>>((const float4*)x, (ushort4*)xb, MDIM * KDIM / 4);
  k_convert_w<<<(NDIM * KDIM) / 256, 256, 0, stream>>>(w, wb);

  k_gemm_nb<<<6144, 256, 0, stream>>>(xb, wb, bias, xtb, fbuf, rbuf);

  k_scan1<<<dim3(32, NSEG), 256, 0, stream>>>(fbuf, xtb, AB);
  k_scan2<<<32, 256, 0, stream>>>(c0, AB, Cin, out + (size_t)L_SEQ * CH);
  k_scan3<<<dim3(32, NSEG), 256, 0, stream>>>(x, fbuf, xtb, rbuf, Cin, out);
}

// Round 14
// 419.170 us; speedup vs baseline: 1.2794x; 1.2794x over previous
//
#include <hip/hip_runtime.h>

#define L_SEQ 2048
#define BATCH 16
#define DDIM  1024
#define MDIM  (L_SEQ * BATCH)   // 32768
#define NDIM  (3 * DDIM)        // 3072
#define KDIM  DDIM              // 1024
#define CH    (BATCH * DDIM)    // 16384
#define NSEG  32
#define SEGL  64                // L_SEQ / NSEG

typedef __attribute__((ext_vector_type(8))) short short8;
typedef __attribute__((ext_vector_type(4))) float f32x4;

static __device__ __forceinline__ unsigned short f2bf(float f) {
  unsigned int u = __builtin_bit_cast(unsigned int, f);
  unsigned int lsb = (u >> 16) & 1u;
  u += 0x7fffu + lsb;
  return (unsigned short)(u >> 16);
}
static __device__ __forceinline__ float bf2f(unsigned short s) {
  unsigned int u = ((unsigned int)s) << 16;
  return __builtin_bit_cast(float, u);
}

static __device__ __forceinline__ void gll16(const void* g, void* l) {
  __builtin_amdgcn_global_load_lds(
      (const __attribute__((address_space(1))) unsigned int*)g,
      (__attribute__((address_space(3))) unsigned int*)l, 16, 0, 0);
}

// ---- converters ----------------------------------------------------------

__global__ void k_convert_x(const float4* __restrict__ x, ushort4* __restrict__ xb, int n4) {
  int i = blockIdx.x * blockDim.x + threadIdx.x;
  int stride = gridDim.x * blockDim.x;
  for (; i < n4; i += stride) {
    float4 v = x[i];
    ushort4 o;
    o.x = f2bf(v.x); o.y = f2bf(v.y); o.z = f2bf(v.z); o.w = f2bf(v.w);
    xb[i] = o;
  }
}

// Wb[n][k] = bf16( W[k][colmap(n)] ): regions {xt, f, r} -> contiguous col ranges
__global__ void k_convert_w(const float* __restrict__ w, unsigned short* __restrict__ wb) {
  int gid = blockIdx.x * 256 + threadIdx.x;   // 3072*1024 total
  int k = gid & (KDIM - 1);
  int n = gid >> 10;
  int col = (n < DDIM) ? 3 * n : (n < 2 * DDIM) ? 3 * (n - DDIM) + 1 : 3 * (n - 2 * DDIM) + 2;
  wb[gid] = f2bf(w[(size_t)k * NDIM + col]);
}

// ---- GEMM (R3 champion, VERBATIM): 256x256, BK=32, 4-buf, reg-pipelined --
// Best measured across 10 structural variants (R2-R12): 244.7-249.0 us,
// MfmaUtil ~38%, 0 bank conflicts, VGPR 128. Wave grid 2x4 (wr=wid>>2,
// wc=wid&3) — R13's failure was mis-transcribing this to 4x2.

#define MFMA1(I, J, A, B) \
  acc[I][J] = __builtin_amdgcn_mfma_f32_16x16x32_bf16(A, B, acc[I][J], 0, 0, 0);

#define MFMAQ(BASE, A0, A1, A2, A3, B0, B1, B2, B3)  \
  MFMA1(BASE + 0, 0, A0, B0) MFMA1(BASE + 0, 1, A0, B1) \
  MFMA1(BASE + 0, 2, A0, B2) MFMA1(BASE + 0, 3, A0, B3) \
  MFMA1(BASE + 1, 0, A1, B0) MFMA1(BASE + 1, 1, A1, B1) \
  MFMA1(BASE + 1, 2, A1, B2) MFMA1(BASE + 1, 3, A1, B3) \
  MFMA1(BASE + 2, 0, A2, B0) MFMA1(BASE + 2, 1, A2, B1) \
  MFMA1(BASE + 2, 2, A2, B2) MFMA1(BASE + 2, 3, A2, B3) \
  MFMA1(BASE + 3, 0, A3, B0) MFMA1(BASE + 3, 1, A3, B1) \
  MFMA1(BASE + 3, 2, A3, B2) MFMA1(BASE + 3, 3, A3, B3)

// One K-tile (BK=32). P0: read cur mh1 A-frags, stage A(+2), MFMA(mh0).
// P1: stage B(+2), fence (vmcnt(4)+barrier), read NEXT tile mh0+B, MFMA(mh1).
#define TILE(J, X0, X1, X2, X3, Y0, Y1, Y2, Y3) do {                         \
  const char* Ab  = LDSc + (((J)) & 3) * 32768;                              \
  const char* AbN = LDSc + (((J) + 1) & 3) * 32768;                          \
  char* Sb = LDSc + (((J) + 2) & 3) * 32768;                                 \
  const int kbS = ((i * 4 + (J) + 2) & 31) * 64;                             \
  q0 = *(const short8*)(Ab + aRd + 4096);                                    \
  q1 = *(const short8*)(Ab + aRd + 5120);                                    \
  q2 = *(const short8*)(Ab + aRd + 6144);                                    \
  q3 = *(const short8*)(Ab + aRd + 7168);                                    \
  gll16(srcA0 + kbS, Sb + dstOff);                                           \
  gll16(srcA1 + kbS, Sb + 8192 + dstOff);                                    \
  __builtin_amdgcn_s_setprio(1);                                             \
  MFMAQ(0, p0, p1, p2, p3, X0, X1, X2, X3)                                   \
  __builtin_amdgcn_s_setprio(0);                                             \
  gll16(srcB0 + kbS, Sb + 16384 + dstOff);                                   \
  gll16(srcB1 + kbS, Sb + 24576 + dstOff);                                   \
  __builtin_amdgcn_sched_barrier(0);                                         \
  asm volatile("s_waitcnt vmcnt(4)" ::: "memory");                           \
  __builtin_amdgcn_s_barrier();                                              \
  __builtin_amdgcn_sched_barrier(0);                                         \
  p0 = *(const short8*)(AbN + aRd);                                          \
  p1 = *(const short8*)(AbN + aRd + 1024);                                   \
  p2 = *(const short8*)(AbN + aRd + 2048);                                   \
  p3 = *(const short8*)(AbN + aRd + 3072);                                   \
  Y0 = *(const short8*)(AbN + 16384 + bRd);                                  \
  Y1 = *(const short8*)(AbN + 16384 + bRd + 1024);                           \
  Y2 = *(const short8*)(AbN + 16384 + bRd + 2048);                           \
  Y3 = *(const short8*)(AbN + 16384 + bRd + 3072);                           \
  __builtin_amdgcn_s_setprio(1);                                             \
  MFMAQ(4, q0, q1, q2, q3, X0, X1, X2, X3)                                   \
  __builtin_amdgcn_s_setprio(0);                                             \
} while (0)

__global__ __launch_bounds__(512, 2) void k_gemm256(
    const unsigned short* __restrict__ xb,   // [M][K] bf16
    const unsigned short* __restrict__ wb,   // [N][K] bf16
    const float* __restrict__ bias,          // [2d]
    unsigned short* __restrict__ xtb,        // [M][d] bf16
    unsigned short* __restrict__ fbuf,       // [M][d] bf16
    unsigned short* __restrict__ rbuf) {     // [M][d] bf16
  __shared__ char LDS[131072];   // 4 buffers x (A 16KB + B 16KB)
  char* LDSc = LDS;

  const int tid  = threadIdx.x;
  const int lane = tid & 63;
  const int wid  = tid >> 6;
  const int wr   = wid >> 2;     // 0..1
  const int wc   = wid & 3;      // 0..3

  // XCD-aware bijective swizzle: 1536 = 8 * 192
  int bid = blockIdx.x;
  int wg = (bid & 7) * 192 + (bid >> 3);
  int mt = wg / 12;
  int nt = wg - mt * 12;
  const int rowBase = mt * 256;
  const int colBase = nt * 256;

  // ds_read bases (chunk-permuted layout: pos = row*4 + (slot ^ ((row>>1)&3)))
  const int l15 = lane & 15;
  const int sl  = lane >> 4;
  const int ra0 = wr * 128 + l15;
  const int rb0 = wc * 64 + l15;
  const int aRd = ra0 * 64 + (sl ^ ((ra0 >> 1) & 3)) * 16;
  const int bRd = rb0 * 64 + (sl ^ ((rb0 >> 1) & 3)) * 16;

  // staging source bases (inverse permutation on global source, linear LDS dest)
  const int p0i = tid, p1i = 512 + tid;
  const int r0 = p0i >> 2, r1 = p1i >> 2;
  const int s0 = (p0i & 3) ^ ((r0 >> 1) & 3);
  const int s1 = (p1i & 3) ^ ((r1 >> 1) & 3);
  const char* srcA0 = (const char*)xb + (size_t)(rowBase + r0) * 2048 + s0 * 16;
  const char* srcA1 = (const char*)xb + (size_t)(rowBase + r1) * 2048 + s1 * 16;
  const char* srcB0 = (const char*)wb + (size_t)(colBase + r0) * 2048 + s0 * 16;
  const char* srcB1 = (const char*)wb + (size_t)(colBase + r1) * 2048 + s1 * 16;
  const int dstOff = wid * 1024;

  f32x4 acc[8][4];
#pragma unroll
  for (int ii = 0; ii < 8; ++ii)
#pragma unroll
    for (int jj = 0; jj < 4; ++jj)
      acc[ii][jj] = (f32x4){0.f, 0.f, 0.f, 0.f};

  // prologue: stage tiles 0 and 1
#pragma unroll
  for (int u = 0; u < 2; ++u) {
    char* ldsu = LDSc + u * 32768;
    gll16(srcA0 + u * 64, ldsu + dstOff);
    gll16(srcA1 + u * 64, ldsu + 8192 + dstOff);
    gll16(srcB0 + u * 64, ldsu + 16384 + dstOff);
    gll16(srcB1 + u * 64, ldsu + 24576 + dstOff);
  }
  asm volatile("s_waitcnt vmcnt(4)" ::: "memory");
  __builtin_amdgcn_s_barrier();
  __builtin_amdgcn_sched_barrier(0);

  short8 p0, p1, p2, p3;   // A mh0 frags
  short8 q0, q1, q2, q3;   // A mh1 frags
  short8 e0, e1, e2, e3;   // B set (even tiles)
  short8 o0, o1, o2, o3;   // B set (odd tiles)

  // preload tile 0: mh0 A frags + B frags
  p0 = *(const short8*)(LDSc + aRd);
  p1 = *(const short8*)(LDSc + aRd + 1024);
  p2 = *(const short8*)(LDSc + aRd + 2048);
  p3 = *(const short8*)(LDSc + aRd + 3072);
  e0 = *(const short8*)(LDSc + 16384 + bRd);
  e1 = *(const short8*)(LDSc + 16384 + bRd + 1024);
  e2 = *(const short8*)(LDSc + 16384 + bRd + 2048);
  e3 = *(const short8*)(LDSc + 16384 + bRd + 3072);

  for (int i = 0; i < 8; ++i) {
    TILE(0, e0, e1, e2, e3, o0, o1, o2, o3);
    TILE(1, o0, o1, o2, o3, e0, e1, e2, e3);
    TILE(2, e0, e1, e2, e3, o0, o1, o2, o3);
    TILE(3, o0, o1, o2, o3, e0, e1, e2, e3);
  }
  asm volatile("s_waitcnt vmcnt(0)" ::: "memory");

  // epilogue: region 0 -> x_tilde (bf16), 1 -> forget, 2 -> reset
  const int region = colBase >> 10;
#pragma unroll
  for (int qm = 0; qm < 2; ++qm) {
#pragma unroll
    for (int m = 0; m < 4; ++m) {
      int grow = rowBase + wr * 128 + qm * 64 + m * 16 + ((lane >> 4) << 2);
#pragma unroll
      for (int n = 0; n < 4; ++n) {
        int gcol = colBase + wc * 64 + n * 16 + (lane & 15);
        f32x4 v = acc[qm * 4 + m][n];
        if (region == 0) {
#pragma unroll
          for (int j = 0; j < 4; ++j)
            xtb[(size_t)(grow + j) * DDIM + gcol] = f2bf(v[j]);
        } else {
          float bv = bias[gcol - DDIM];
          unsigned short* dst = (region == 1) ? fbuf : rbuf;
          int lcol = gcol - (region << 10);
#pragma unroll
          for (int j = 0; j < 4; ++j) {
            float sg = 1.0f / (1.0f + __expf(-(v[j] + bv)));
            dst[(size_t)(grow + j) * DDIM + lcol] = f2bf(sg);
          }
        }
      }
    }
  }
}

// ---- segmented scan ------------------------------------------------------
// pass 1: per (segment, 2 channel-pairs) affine state; uint2 (8B) loads (G13)

__global__ __launch_bounds__(256) void k_scan1(
    const unsigned short* __restrict__ fbuf,
    const unsigned short* __restrict__ xtb,
    float4* __restrict__ AB) {
  int idx = blockIdx.x * 256 + threadIdx.x;       // 0..4095
  int seg = blockIdx.y;
  int pp = idx * 2;                                // first of 2 channel-pairs
  size_t base = (size_t)seg * SEGL * CH + (size_t)pp * 2;
  const uint2* fp = (const uint2*)(fbuf + base);
  const uint2* xp = (const uint2*)(xtb + base);
  float a[4], b[4];
#pragma unroll
  for (int e = 0; e < 4; ++e) { a[e] = 1.f; b[e] = 0.f; }
#pragma unroll 8
  for (int s = 0; s < SEGL; ++s) {
    uint2 fv = fp[(size_t)s * (CH / 4)];
    uint2 xv = xp[(size_t)s * (CH / 4)];
    unsigned int fw[2] = {fv.x, fv.y};
    unsigned int xw[2] = {xv.x, xv.y};
#pragma unroll
    for (int q = 0; q < 2; ++q) {
      float f0 = bf2f((unsigned short)fw[q]), f1 = bf2f((unsigned short)(fw[q] >> 16));
      float x0 = bf2f((unsigned short)xw[q]), x1 = bf2f((unsigned short)(xw[q] >> 16));
      b[2 * q]     = (b[2 * q] - x0) * f0 + x0;      a[2 * q]     *= f0;
      b[2 * q + 1] = (b[2 * q + 1] - x1) * f1 + x1;  a[2 * q + 1] *= f1;
    }
  }
  AB[(size_t)seg * (CH / 2) + pp]     = (float4){a[0], b[0], a[1], b[1]};
  AB[(size_t)seg * (CH / 2) + pp + 1] = (float4){a[2], b[2], a[3], b[3]};
}

// pass 2: scan 32 segment states per channel; emit per-segment c_in and c_last

__global__ __launch_bounds__(256) void k_scan2(
    const float* __restrict__ c0,
    const float4* __restrict__ AB,
    float* __restrict__ Cin,
    float* __restrict__ clast) {
  int chp = blockIdx.x * 256 + threadIdx.x;       // 0..8191
  float2 cc = ((const float2*)c0)[chp];
  float ca = cc.x, cb = cc.y;
#pragma unroll
  for (int s = 0; s < NSEG; ++s) {
    ((float2*)Cin)[(size_t)s * (CH / 2) + chp] = (float2){ca, cb};
    float4 ab = AB[(size_t)s * (CH / 2) + chp];
    ca = ca * ab.x + ab.y;
    cb = cb * ab.z + ab.w;
  }
  ((float2*)clast)[chp] = (float2){ca, cb};
}

// pass 3: recompute c within segment from c_in; emit h

__global__ __launch_bounds__(256) void k_scan3(
    const float* __restrict__ x,
    const unsigned short* __restrict__ fbuf,
    const unsigned short* __restrict__ xtb,
    const unsigned short* __restrict__ rbuf,
    const float* __restrict__ Cin,
    float* __restrict__ h) {
  int chp = blockIdx.x * 256 + threadIdx.x;
  int seg = blockIdx.y;
  float2 cc = ((const float2*)Cin)[(size_t)seg * (CH / 2) + chp];
  float ca = cc.x, cb = cc.y;
  size_t base = (size_t)seg * SEGL * CH + chp * 2;
  const unsigned int* fp = (const unsigned int*)(fbuf + base);
  const unsigned int* tp = (const unsigned int*)(xtb + base);
  const unsigned int* rp = (const unsigned int*)(rbuf + base);
  const float2* xp = (const float2*)(x + base);
  float2* hp = (float2*)(h + base);
#pragma unroll 4
  for (int s = 0; s < SEGL; ++s) {
    unsigned int fv = fp[(size_t)s * (CH / 2)];
    unsigned int tv = tp[(size_t)s * (CH / 2)];
    unsigned int rv = rp[(size_t)s * (CH / 2)];
    float2 xv = xp[(size_t)s * (CH / 2)];
    float f0 = bf2f((unsigned short)fv), f1 = bf2f((unsigned short)(fv >> 16));
    float t0 = bf2f((unsigned short)tv), t1 = bf2f((unsigned short)(tv >> 16));
    float r0 = bf2f((unsigned short)rv), r1 = bf2f((unsigned short)(rv >> 16));
    ca = (ca - t0) * f0 + t0;
    cb = (cb - t1) * f1 + t1;
    float e0 = __expf(-2.f * fabsf(ca));
    float e1 = __expf(-2.f * fabsf(cb));
    float g0 = copysignf((1.f - e0) / (1.f + e0), ca);
    float g1 = copysignf((1.f - e1) / (1.f + e1), cb);
    float h0 = (g0 - xv.x) * r0 + xv.x;
    float h1 = (g1 - xv.y) * r1 + xv.y;
    hp[(size_t)s * (CH / 2)] = (float2){h0, h1};
  }
}

// ---- launch --------------------------------------------------------------

extern "C" void kernel_launch(void* const* d_in, const int* in_sizes, int n_in,
                              void* d_out, int out_size, void* d_ws, size_t ws_size,
                              hipStream_t stream) {
  const float* x    = (const float*)d_in[0];
  const float* w    = (const float*)d_in[1];
  const float* bias = (const float*)d_in[2];
  const float* c0   = (const float*)d_in[3];
  float* out = (float*)d_out;
  char* ws = (char*)d_ws;

  unsigned short* wb   = (unsigned short*)(ws);
  float4*         AB   = (float4*)(ws);
  float*          Cin  = (float*)(ws + 4194304);
  unsigned short* xtb  = (unsigned short*)(ws + 6291456);
  unsigned short* fbuf = (unsigned short*)(ws + 73400320);
  unsigned short* rbuf = (unsigned short*)(ws + 140509184);
  unsigned short* xb = (unsigned short*)d_out;   // h-region, dead until scan3

  k_convert_x<<<2048, 256, 0, stream>>>((const float4*)x, (ushort4*)xb, MDIM * KDIM / 4);
  k_convert_w<<<(NDIM * KDIM) / 256, 256, 0, stream>>>(w, wb);

  k_gemm256<<<1536, 512, 0, stream>>>(xb, wb, bias, xtb, fbuf, rbuf);

  k_scan1<<<dim3(16, NSEG), 256, 0, stream>>>(fbuf, xtb, AB);
  k_scan2<<<32, 256, 0, stream>>>(c0, AB, Cin, out + (size_t)L_SEQ * CH);
  k_scan3<<<dim3(32, NSEG), 256, 0, stream>>>(x, fbuf, xtb, rbuf, Cin, out);
}

// Round 15
// 408.571 us; speedup vs baseline: 1.3126x; 1.0259x over previous
//
#include <hip/hip_runtime.h>

#define L_SEQ 2048
#define BATCH 16
#define DDIM  1024
#define MDIM  (L_SEQ * BATCH)   // 32768
#define NDIM  (3 * DDIM)        // 3072
#define KDIM  DDIM              // 1024
#define CH    (BATCH * DDIM)    // 16384
#define NSEG  32
#define SEGL  64                // L_SEQ / NSEG

typedef __attribute__((ext_vector_type(8))) short short8;
typedef __attribute__((ext_vector_type(4))) float f32x4;

static __device__ __forceinline__ unsigned short f2bf(float f) {
  unsigned int u = __builtin_bit_cast(unsigned int, f);
  unsigned int lsb = (u >> 16) & 1u;
  u += 0x7fffu + lsb;
  return (unsigned short)(u >> 16);
}
static __device__ __forceinline__ float bf2f(unsigned short s) {
  unsigned int u = ((unsigned int)s) << 16;
  return __builtin_bit_cast(float, u);
}

static __device__ __forceinline__ void gll16(const void* g, void* l) {
  __builtin_amdgcn_global_load_lds(
      (const __attribute__((address_space(1))) unsigned int*)g,
      (__attribute__((address_space(3))) unsigned int*)l, 16, 0, 0);
}

// ---- converters ----------------------------------------------------------

__global__ void k_convert_x(const float4* __restrict__ x, ushort4* __restrict__ xb, int n4) {
  int i = blockIdx.x * blockDim.x + threadIdx.x;
  int stride = gridDim.x * blockDim.x;
  for (; i < n4; i += stride) {
    float4 v = x[i];
    ushort4 o;
    o.x = f2bf(v.x); o.y = f2bf(v.y); o.z = f2bf(v.z); o.w = f2bf(v.w);
    xb[i] = o;
  }
}

// Wb[n][k] = bf16( W[k][colmap(n)] ): regions {xt, f, r} -> contiguous col ranges
__global__ void k_convert_w(const float* __restrict__ w, unsigned short* __restrict__ wb) {
  int gid = blockIdx.x * 256 + threadIdx.x;   // 3072*1024 total
  int k = gid & (KDIM - 1);
  int n = gid >> 10;
  int col = (n < DDIM) ? 3 * n : (n < 2 * DDIM) ? 3 * (n - DDIM) + 1 : 3 * (n - 2 * DDIM) + 2;
  wb[gid] = f2bf(w[(size_t)k * NDIM + col]);
}

// ---- GEMM (R3 champion, VERBATIM): 256x256, BK=32, 4-buf, reg-pipelined --
// Best measured across 10 structural variants (R2-R12): 244.7-249.0 us,
// MfmaUtil ~38%, 0 bank conflicts, VGPR 128. Wave grid 2x4 (wr=wid>>2, wc=wid&3).

#define MFMA1(I, J, A, B) \
  acc[I][J] = __builtin_amdgcn_mfma_f32_16x16x32_bf16(A, B, acc[I][J], 0, 0, 0);

#define MFMAQ(BASE, A0, A1, A2, A3, B0, B1, B2, B3)  \
  MFMA1(BASE + 0, 0, A0, B0) MFMA1(BASE + 0, 1, A0, B1) \
  MFMA1(BASE + 0, 2, A0, B2) MFMA1(BASE + 0, 3, A0, B3) \
  MFMA1(BASE + 1, 0, A1, B0) MFMA1(BASE + 1, 1, A1, B1) \
  MFMA1(BASE + 1, 2, A1, B2) MFMA1(BASE + 1, 3, A1, B3) \
  MFMA1(BASE + 2, 0, A2, B0) MFMA1(BASE + 2, 1, A2, B1) \
  MFMA1(BASE + 2, 2, A2, B2) MFMA1(BASE + 2, 3, A2, B3) \
  MFMA1(BASE + 3, 0, A3, B0) MFMA1(BASE + 3, 1, A3, B1) \
  MFMA1(BASE + 3, 2, A3, B2) MFMA1(BASE + 3, 3, A3, B3)

// One K-tile (BK=32). P0: read cur mh1 A-frags, stage A(+2), MFMA(mh0).
// P1: stage B(+2), fence (vmcnt(4)+barrier), read NEXT tile mh0+B, MFMA(mh1).
#define TILE(J, X0, X1, X2, X3, Y0, Y1, Y2, Y3) do {                         \
  const char* Ab  = LDSc + (((J)) & 3) * 32768;                              \
  const char* AbN = LDSc + (((J) + 1) & 3) * 32768;                          \
  char* Sb = LDSc + (((J) + 2) & 3) * 32768;                                 \
  const int kbS = ((i * 4 + (J) + 2) & 31) * 64;                             \
  q0 = *(const short8*)(Ab + aRd + 4096);                                    \
  q1 = *(const short8*)(Ab + aRd + 5120);                                    \
  q2 = *(const short8*)(Ab + aRd + 6144);                                    \
  q3 = *(const short8*)(Ab + aRd + 7168);                                    \
  gll16(srcA0 + kbS, Sb + dstOff);                                           \
  gll16(srcA1 + kbS, Sb + 8192 + dstOff);                                    \
  __builtin_amdgcn_s_setprio(1);                                             \
  MFMAQ(0, p0, p1, p2, p3, X0, X1, X2, X3)                                   \
  __builtin_amdgcn_s_setprio(0);                                             \
  gll16(srcB0 + kbS, Sb + 16384 + dstOff);                                   \
  gll16(srcB1 + kbS, Sb + 24576 + dstOff);                                   \
  __builtin_amdgcn_sched_barrier(0);                                         \
  asm volatile("s_waitcnt vmcnt(4)" ::: "memory");                           \
  __builtin_amdgcn_s_barrier();                                              \
  __builtin_amdgcn_sched_barrier(0);                                         \
  p0 = *(const short8*)(AbN + aRd);                                          \
  p1 = *(const short8*)(AbN + aRd + 1024);                                   \
  p2 = *(const short8*)(AbN + aRd + 2048);                                   \
  p3 = *(const short8*)(AbN + aRd + 3072);                                   \
  Y0 = *(const short8*)(AbN + 16384 + bRd);                                  \
  Y1 = *(const short8*)(AbN + 16384 + bRd + 1024);                           \
  Y2 = *(const short8*)(AbN + 16384 + bRd + 2048);                           \
  Y3 = *(const short8*)(AbN + 16384 + bRd + 3072);                           \
  __builtin_amdgcn_s_setprio(1);                                             \
  MFMAQ(4, q0, q1, q2, q3, X0, X1, X2, X3)                                   \
  __builtin_amdgcn_s_setprio(0);                                             \
} while (0)

__global__ __launch_bounds__(512, 2) void k_gemm256(
    const unsigned short* __restrict__ xb,   // [M][K] bf16
    const unsigned short* __restrict__ wb,   // [N][K] bf16
    const float* __restrict__ bias,          // [2d]
    unsigned short* __restrict__ xtb,        // [M][d] bf16
    unsigned short* __restrict__ fbuf,       // [M][d] bf16
    unsigned short* __restrict__ rbuf) {     // [M][d] bf16
  __shared__ char LDS[131072];   // 4 buffers x (A 16KB + B 16KB)
  char* LDSc = LDS;

  const int tid  = threadIdx.x;
  const int lane = tid & 63;
  const int wid  = tid >> 6;
  const int wr   = wid >> 2;     // 0..1
  const int wc   = wid & 3;      // 0..3

  // XCD-aware bijective swizzle: 1536 = 8 * 192
  int bid = blockIdx.x;
  int wg = (bid & 7) * 192 + (bid >> 3);
  int mt = wg / 12;
  int nt = wg - mt * 12;
  const int rowBase = mt * 256;
  const int colBase = nt * 256;

  // ds_read bases (chunk-permuted layout: pos = row*4 + (slot ^ ((row>>1)&3)))
  const int l15 = lane & 15;
  const int sl  = lane >> 4;
  const int ra0 = wr * 128 + l15;
  const int rb0 = wc * 64 + l15;
  const int aRd = ra0 * 64 + (sl ^ ((ra0 >> 1) & 3)) * 16;
  const int bRd = rb0 * 64 + (sl ^ ((rb0 >> 1) & 3)) * 16;

  // staging source bases (inverse permutation on global source, linear LDS dest)
  const int p0i = tid, p1i = 512 + tid;
  const int r0 = p0i >> 2, r1 = p1i >> 2;
  const int s0 = (p0i & 3) ^ ((r0 >> 1) & 3);
  const int s1 = (p1i & 3) ^ ((r1 >> 1) & 3);
  const char* srcA0 = (const char*)xb + (size_t)(rowBase + r0) * 2048 + s0 * 16;
  const char* srcA1 = (const char*)xb + (size_t)(rowBase + r1) * 2048 + s1 * 16;
  const char* srcB0 = (const char*)wb + (size_t)(colBase + r0) * 2048 + s0 * 16;
  const char* srcB1 = (const char*)wb + (size_t)(colBase + r1) * 2048 + s1 * 16;
  const int dstOff = wid * 1024;

  f32x4 acc[8][4];
#pragma unroll
  for (int ii = 0; ii < 8; ++ii)
#pragma unroll
    for (int jj = 0; jj < 4; ++jj)
      acc[ii][jj] = (f32x4){0.f, 0.f, 0.f, 0.f};

  // prologue: stage tiles 0 and 1
#pragma unroll
  for (int u = 0; u < 2; ++u) {
    char* ldsu = LDSc + u * 32768;
    gll16(srcA0 + u * 64, ldsu + dstOff);
    gll16(srcA1 + u * 64, ldsu + 8192 + dstOff);
    gll16(srcB0 + u * 64, ldsu + 16384 + dstOff);
    gll16(srcB1 + u * 64, ldsu + 24576 + dstOff);
  }
  asm volatile("s_waitcnt vmcnt(4)" ::: "memory");
  __builtin_amdgcn_s_barrier();
  __builtin_amdgcn_sched_barrier(0);

  short8 p0, p1, p2, p3;   // A mh0 frags
  short8 q0, q1, q2, q3;   // A mh1 frags
  short8 e0, e1, e2, e3;   // B set (even tiles)
  short8 o0, o1, o2, o3;   // B set (odd tiles)

  // preload tile 0: mh0 A frags + B frags
  p0 = *(const short8*)(LDSc + aRd);
  p1 = *(const short8*)(LDSc + aRd + 1024);
  p2 = *(const short8*)(LDSc + aRd + 2048);
  p3 = *(const short8*)(LDSc + aRd + 3072);
  e0 = *(const short8*)(LDSc + 16384 + bRd);
  e1 = *(const short8*)(LDSc + 16384 + bRd + 1024);
  e2 = *(const short8*)(LDSc + 16384 + bRd + 2048);
  e3 = *(const short8*)(LDSc + 16384 + bRd + 3072);

  for (int i = 0; i < 8; ++i) {
    TILE(0, e0, e1, e2, e3, o0, o1, o2, o3);
    TILE(1, o0, o1, o2, o3, e0, e1, e2, e3);
    TILE(2, e0, e1, e2, e3, o0, o1, o2, o3);
    TILE(3, o0, o1, o2, o3, e0, e1, e2, e3);
  }
  asm volatile("s_waitcnt vmcnt(0)" ::: "memory");

  // epilogue: region 0 -> x_tilde (bf16), 1 -> forget, 2 -> reset
  const int region = colBase >> 10;
#pragma unroll
  for (int qm = 0; qm < 2; ++qm) {
#pragma unroll
    for (int m = 0; m < 4; ++m) {
      int grow = rowBase + wr * 128 + qm * 64 + m * 16 + ((lane >> 4) << 2);
#pragma unroll
      for (int n = 0; n < 4; ++n) {
        int gcol = colBase + wc * 64 + n * 16 + (lane & 15);
        f32x4 v = acc[qm * 4 + m][n];
        if (region == 0) {
#pragma unroll
          for (int j = 0; j < 4; ++j)
            xtb[(size_t)(grow + j) * DDIM + gcol] = f2bf(v[j]);
        } else {
          float bv = bias[gcol - DDIM];
          unsigned short* dst = (region == 1) ? fbuf : rbuf;
          int lcol = gcol - (region << 10);
#pragma unroll
          for (int j = 0; j < 4; ++j) {
            float sg = 1.0f / (1.0f + __expf(-(v[j] + bv)));
            dst[(size_t)(grow + j) * DDIM + lcol] = f2bf(sg);
          }
        }
      }
    }
  }
}

// ---- segmented scan (R5-exact versions — session-best non-GEMM) ----------
// pass 1: per (segment, channel-pair) affine state a = prod f, b = scan from 0

__global__ __launch_bounds__(256) void k_scan1(
    const unsigned short* __restrict__ fbuf,
    const unsigned short* __restrict__ xtb,
    float4* __restrict__ AB) {
  int chp = blockIdx.x * 256 + threadIdx.x;       // 0..8191 channel pairs
  int seg = blockIdx.y;
  size_t base = (size_t)seg * SEGL * CH + chp * 2;
  const unsigned int* fp = (const unsigned int*)(fbuf + base);
  const unsigned int* xp = (const unsigned int*)(xtb + base);
  float a0 = 1.f, a1 = 1.f, b0 = 0.f, b1 = 0.f;
#pragma unroll 8
  for (int s = 0; s < SEGL; ++s) {
    unsigned int fv = fp[(size_t)s * (CH / 2)];
    unsigned int xv = xp[(size_t)s * (CH / 2)];
    float f0 = bf2f((unsigned short)fv), f1 = bf2f((unsigned short)(fv >> 16));
    float x0 = bf2f((unsigned short)xv), x1 = bf2f((unsigned short)(xv >> 16));
    b0 = (b0 - x0) * f0 + x0;  a0 *= f0;
    b1 = (b1 - x1) * f1 + x1;  a1 *= f1;
  }
  AB[(size_t)seg * (CH / 2) + chp] = (float4){a0, b0, a1, b1};
}

// pass 2: scan 32 segment states per channel; emit per-segment c_in and c_last

__global__ __launch_bounds__(256) void k_scan2(
    const float* __restrict__ c0,
    const float4* __restrict__ AB,
    float* __restrict__ Cin,
    float* __restrict__ clast) {
  int chp = blockIdx.x * 256 + threadIdx.x;       // 0..8191
  float2 cc = ((const float2*)c0)[chp];
  float ca = cc.x, cb = cc.y;
#pragma unroll
  for (int s = 0; s < NSEG; ++s) {
    ((float2*)Cin)[(size_t)s * (CH / 2) + chp] = (float2){ca, cb};
    float4 ab = AB[(size_t)s * (CH / 2) + chp];
    ca = ca * ab.x + ab.y;
    cb = cb * ab.z + ab.w;
  }
  ((float2*)clast)[chp] = (float2){ca, cb};
}

// pass 3: recompute c within segment from c_in; emit h

__global__ __launch_bounds__(256) void k_scan3(
    const float* __restrict__ x,
    const unsigned short* __restrict__ fbuf,
    const unsigned short* __restrict__ xtb,
    const unsigned short* __restrict__ rbuf,
    const float* __restrict__ Cin,
    float* __restrict__ h) {
  int chp = blockIdx.x * 256 + threadIdx.x;
  int seg = blockIdx.y;
  float2 cc = ((const float2*)Cin)[(size_t)seg * (CH / 2) + chp];
  float ca = cc.x, cb = cc.y;
  size_t base = (size_t)seg * SEGL * CH + chp * 2;
  const unsigned int* fp = (const unsigned int*)(fbuf + base);
  const unsigned int* tp = (const unsigned int*)(xtb + base);
  const unsigned int* rp = (const unsigned int*)(rbuf + base);
  const float2* xp = (const float2*)(x + base);
  float2* hp = (float2*)(h + base);
#pragma unroll 4
  for (int s = 0; s < SEGL; ++s) {
    unsigned int fv = fp[(size_t)s * (CH / 2)];
    unsigned int tv = tp[(size_t)s * (CH / 2)];
    unsigned int rv = rp[(size_t)s * (CH / 2)];
    float2 xv = xp[(size_t)s * (CH / 2)];
    float f0 = bf2f((unsigned short)fv), f1 = bf2f((unsigned short)(fv >> 16));
    float t0 = bf2f((unsigned short)tv), t1 = bf2f((unsigned short)(tv >> 16));
    float r0 = bf2f((unsigned short)rv), r1 = bf2f((unsigned short)(rv >> 16));
    ca = (ca - t0) * f0 + t0;
    cb = (cb - t1) * f1 + t1;
    float e0 = __expf(-2.f * fabsf(ca));
    float e1 = __expf(-2.f * fabsf(cb));
    float g0 = copysignf((1.f - e0) / (1.f + e0), ca);
    float g1 = copysignf((1.f - e1) / (1.f + e1), cb);
    float h0 = (g0 - xv.x) * r0 + xv.x;
    float h1 = (g1 - xv.y) * r1 + xv.y;
    hp[(size_t)s * (CH / 2)] = (float2){h0, h1};
  }
}

// ---- launch --------------------------------------------------------------

extern "C" void kernel_launch(void* const* d_in, const int* in_sizes, int n_in,
                              void* d_out, int out_size, void* d_ws, size_t ws_size,
                              hipStream_t stream) {
  const float* x    = (const float*)d_in[0];
  const float* w    = (const float*)d_in[1];
  const float* bias = (const float*)d_in[2];
  const float* c0   = (const float*)d_in[3];
  float* out = (float*)d_out;
  char* ws = (char*)d_ws;

  unsigned short* wb   = (unsigned short*)(ws);
  float4*         AB   = (float4*)(ws);
  float*          Cin  = (float*)(ws + 4194304);
  unsigned short* xtb  = (unsigned short*)(ws + 6291456);
  unsigned short* fbuf = (unsigned short*)(ws + 73400320);
  unsigned short* rbuf = (unsigned short*)(ws + 140509184);
  unsigned short* xb = (unsigned short*)d_out;   // h-region, dead until scan3

  k_convert_x<<<2048, 256, 0, stream>>>((const float4*)x, (ushort4*)xb, MDIM * KDIM / 4);
  k_convert_w<<<(NDIM * KDIM) / 256, 256, 0, stream>>>(w, wb);

  k_gemm256<<<1536, 512, 0, stream>>>(xb, wb, bias, xtb, fbuf, rbuf);

  k_scan1<<<dim3(32, NSEG), 256, 0, stream>>>(fbuf, xtb, AB);
  k_scan2<<<32, 256, 0, stream>>>(c0, AB, Cin, out + (size_t)L_SEQ * CH);
  k_scan3<<<dim3(32, NSEG), 256, 0, stream>>>(x, fbuf, xtb, rbuf, Cin, out);
}